// Round 3
// baseline (530.918 us; speedup 1.0000x reference)
//
#include <hip/hip_runtime.h>
#include <float.h>
#include <math.h>

#define NN 8192
#define DH 256
#define KNN 10
#define TSTEPS 10
#define EPSC 0.1f
#define CTILE 1024          // candidates per half staged in LDS per tile

typedef short s8v __attribute__((ext_vector_type(8)));
typedef float f4v __attribute__((ext_vector_type(4)));

__device__ __forceinline__ float bf2f(unsigned short u) {
    union { unsigned u; float f; } c; c.u = ((unsigned)u) << 16; return c.f;
}
__device__ __forceinline__ unsigned short f2bf(float f) {
    union { float f; unsigned u; } c; c.f = f;
    unsigned r = c.u + 0x7FFF + ((c.u >> 16) & 1);
    return (unsigned short)(r >> 16);
}

// Replicated sorted top-10 (identical in all lanes). Insert of a wave-uniform
// candidate costs ~50 VALU, ZERO cross-lane ops. Strict '<' keeps earlier
// (lower-index) arrival on ties.
#define DECL_TOP10 \
    float b0=FLT_MAX,b1=FLT_MAX,b2=FLT_MAX,b3=FLT_MAX,b4=FLT_MAX, \
          b5=FLT_MAX,b6=FLT_MAX,b7=FLT_MAX,b8=FLT_MAX,b9=FLT_MAX; \
    int   i0=-1,i1=-1,i2=-1,i3=-1,i4=-1,i5=-1,i6=-1,i7=-1,i8=-1,i9=-1;

#define BSTEP(bk, ik) { \
    bool  _s  = _t < bk; \
    float _bn = fminf(bk, _t); \
    _t        = fmaxf(bk, _t); \
    int   _in = _s ? _it : ik; \
    _it       = _s ? ik : _it; \
    bk = _bn; ik = _in; \
}

#define BUBBLE10(dv, jv) do { \
    float _t = (dv); int _it = (jv); \
    BSTEP(b0, i0) BSTEP(b1, i1) BSTEP(b2, i2) BSTEP(b3, i3) BSTEP(b4, i4) \
    BSTEP(b5, i5) BSTEP(b6, i6) BSTEP(b7, i7) BSTEP(b8, i8) BSTEP(b9, i9) \
} while (0)

// select value of rank 'lane' from replicated scalars (cndmask ladder)
#define RANK_LADDER(dv, jv) \
    float dv = b0; int jv = i0; \
    dv = (lane >= 1) ? b1 : dv;  jv = (lane >= 1) ? i1 : jv; \
    dv = (lane >= 2) ? b2 : dv;  jv = (lane >= 2) ? i2 : jv; \
    dv = (lane >= 3) ? b3 : dv;  jv = (lane >= 3) ? i3 : jv; \
    dv = (lane >= 4) ? b4 : dv;  jv = (lane >= 4) ? i4 : jv; \
    dv = (lane >= 5) ? b5 : dv;  jv = (lane >= 5) ? i5 : jv; \
    dv = (lane >= 6) ? b6 : dv;  jv = (lane >= 6) ? i6 : jv; \
    dv = (lane >= 7) ? b7 : dv;  jv = (lane >= 7) ? i7 : jv; \
    dv = (lane >= 8) ? b8 : dv;  jv = (lane >= 8) ? i8 : jv; \
    dv = (lane >= 9) ? b9 : dv;  jv = (lane >= 9) ? i9 : jv;

// ---------------- conv_ws [3][256][256] (k,n) -> bf16 Wt [3][n][k] ------------
__global__ void prep_wt(const float* __restrict__ W, unsigned short* __restrict__ Wt) {
    int e = blockIdx.x * 256 + threadIdx.x;
    int g = e >> 16; int rem = e & 65535;
    int n = rem >> 8; int k = rem & 255;
    Wt[e] = f2bf(W[g * 65536 + k * 256 + n]);
}

// ---------------- pos4[j] = {x, y, z, |p|^2} ----------------------------------
__global__ void prep_pos(const float* __restrict__ pos, float4* __restrict__ pos4) {
    int j = blockIdx.x * 256 + threadIdx.x;
    float x = pos[j * 3], y = pos[j * 3 + 1], z = pos[j * 3 + 2];
    float4 v; v.x = x; v.y = y; v.z = z; v.w = x * x + y * y + z * z;
    pos4[j] = v;
}

// ---------------- kNN: 2 waves per query, replicated top-10, readlane pops ----
// Each query is scanned by two waves (half 0: j<4096, half 1: j>=4096), each
// keeping a replicated sorted top-10. Insert of a passing candidate:
// s_ff1 -> readlane (VALU) broadcast -> 50-VALU bubble network. No DS ops on
// the insert path (R2's 5 serialized shfl per insert was the latency wall).
// Halves merge once via LDS at the end; half-0 indices < half-1 indices, so
// strict '<' keeps jax.lax.top_k tie order.
__launch_bounds__(512)
__global__ void knn_wave(const float* __restrict__ pos, const float4* __restrict__ pos4,
                         int* __restrict__ nbr) {
    __shared__ float4 cand[2 * CTILE];
    __shared__ float md[4][KNN];
    __shared__ int   mj[4][KNN];
    int tid = threadIdx.x;
    int wv = tid >> 7;                 // query slot 0..3
    int half = (tid >> 6) & 1;         // which half of the index space
    int lane = tid & 63;
    int i = blockIdx.x * 4 + wv;
    float xi = pos[i * 3], yi = pos[i * 3 + 1], zi = pos[i * 3 + 2];
    float sqi = xi * xi + yi * yi + zi * zi;

    DECL_TOP10;

    for (int tile = 0; tile < 4; ++tile) {
        __syncthreads();
        for (int t = tid; t < 2 * CTILE; t += 512) {
            int h = t >> 10, off = t & 1023;
            cand[t] = pos4[(tile + h * 4) * CTILE + off];
        }
        __syncthreads();
        int jbase = (tile + half * 4) * CTILE;
        const float4* cbase = cand + half * CTILE;
#pragma unroll 4
        for (int u = 0; u < CTILE / 64; ++u) {
            float4 c = cbase[u * 64 + lane];
            int j = jbase + u * 64 + lane;
            float m = c.x * xi + c.y * yi + c.z * zi;
            float d = (sqi + c.w) - 2.0f * m;
            if (j == i) d = FLT_MAX;           // self-exclusion, branchless
            unsigned long long mask = __ballot(d < b9);
            while (mask) {
                int l = __ffsll(mask) - 1;
                mask &= mask - 1;
                float dc = __int_as_float(__builtin_amdgcn_readlane(__float_as_int(d), l));
                if (dc < b9) {                 // recheck vs updated threshold
                    int jc = __builtin_amdgcn_readlane(j, l);
                    BUBBLE10(dc, jc);
                }
            }
        }
    }

    {
        RANK_LADDER(dv, jv);
        __syncthreads();
        if (half == 1 && lane < KNN) { md[wv][lane] = dv; mj[wv][lane] = jv; }
    }
    __syncthreads();
    if (half == 0) {
        for (int q = 0; q < KNN; q++) {        // uniform LDS broadcast reads
            float dq = md[wv][q]; int jq = mj[wv][q];
            BUBBLE10(dq, jq);
        }
        RANK_LADDER(dv2, jv2);
        if (lane < KNN) nbr[i * KNN + lane] = jv2;
    }
}

// ---------------- h = lm@emb_w + emb_b ; x = h@rw + rb ------------------------
__global__ void emb_kernel(const float* __restrict__ lm, const float* __restrict__ ew,
                           const float* __restrict__ eb, const float* __restrict__ rw,
                           const float* __restrict__ rb,
                           float* __restrict__ hdo, unsigned short* __restrict__ hbf,
                           float* __restrict__ xout) {
    __shared__ float s0[4], s1[4], s2[4];
    int i = blockIdx.x, d = threadIdx.x;
    float a0 = lm[i * 3], a1 = lm[i * 3 + 1], a2 = lm[i * 3 + 2];
    float h = eb[d] + a0 * ew[d] + a1 * ew[256 + d] + a2 * ew[512 + d];
    hdo[i * 256 + d] = h;
    hbf[i * 256 + d] = f2bf(h);
    float p0 = h * rw[d * 3], p1 = h * rw[d * 3 + 1], p2 = h * rw[d * 3 + 2];
    for (int off = 32; off; off >>= 1) {
        p0 += __shfl_down(p0, off, 64);
        p1 += __shfl_down(p1, off, 64);
        p2 += __shfl_down(p2, off, 64);
    }
    int lane = d & 63, wid = d >> 6;
    if (lane == 0) { s0[wid] = p0; s1[wid] = p1; s2[wid] = p2; }
    __syncthreads();
    if (d == 0) {
        xout[i * 3 + 0] = s0[0] + s0[1] + s0[2] + s0[3] + rb[0];
        xout[i * 3 + 1] = s1[0] + s1[1] + s1[2] + s1[3] + rb[1];
        xout[i * 3 + 2] = s2[0] + s2[1] + s2[2] + s2[3] + rb[2];
    }
}

// ---------------- hop-1: x1[i] = 0.1 * sum_{j in nbr(i)} hbf[j] ---------------
__global__ void agg_kernel(const unsigned short* __restrict__ src,
                           unsigned short* __restrict__ dst,
                           const int* __restrict__ nbr) {
    int tid = threadIdx.x;
    int wid = tid >> 6, lane = tid & 63;
    int node = blockIdx.x * 4 + wid;
    int d0 = lane * 4;
    float a0 = 0.f, a1 = 0.f, a2 = 0.f, a3 = 0.f;
    const int* nb = nbr + node * KNN;
    for (int q = 0; q < KNN; q++) {
        int j = nb[q];
        uint2 v = *(const uint2*)(src + j * 256 + d0);
        a0 += bf2f((unsigned short)(v.x & 0xffff));
        a1 += bf2f((unsigned short)(v.x >> 16));
        a2 += bf2f((unsigned short)(v.y & 0xffff));
        a3 += bf2f((unsigned short)(v.y >> 16));
    }
    uint2 o;
    o.x = (unsigned)f2bf(a0 * 0.1f) | ((unsigned)f2bf(a1 * 0.1f) << 16);
    o.y = (unsigned)f2bf(a2 * 0.1f) | ((unsigned)f2bf(a3 * 0.1f) << 16);
    *(uint2*)(dst + node * 256 + d0) = o;
}

// ------- fused: hop-2 gather + GEMM + Euler + readout. M-tile 16, grid 512 ----
// 2 blocks/CU so an independent block overlaps each barrier drain (R2 ran
// 1 block/CU: every __syncthreads drained the whole CU).
__launch_bounds__(256)
__global__ void gemm_step(unsigned short* hbf,
                          const unsigned short* __restrict__ x1,
                          const int* __restrict__ nbr,
                          const unsigned short* __restrict__ Wt,
                          const float* __restrict__ cb,
                          const float* __restrict__ rw, const float* __restrict__ rb,
                          float* hdo, float* __restrict__ yout, float* yfin) {
    __shared__ __align__(16) short Al[16 * 72];
    __shared__ __align__(16) short Bl[256 * 72];
    __shared__ __align__(16) short X2[16 * 264];
    __shared__ float rwl[768];
    __shared__ float cbl[256];
    __shared__ float yred[4][4][4][3];     // [wave][quad][r][xyz]

    int tid = threadIdx.x;
    int m0 = blockIdx.x * 16;
    for (int idx = tid; idx < 768; idx += 256) rwl[idx] = rw[idx];
    cbl[tid] = cb[tid];

    // ---- fused hop-2 aggregation: X2[row][:] = bf16(0.1 * sum x1[nbr[row]]) ----
    {
        int row = tid >> 4, cg = tid & 15;          // 16 threads per row, 16 dims each
        const int* nb = nbr + (m0 + row) * KNN;
        float a[16];
#pragma unroll
        for (int e = 0; e < 16; e++) a[e] = 0.f;
        for (int q = 0; q < KNN; q++) {
            int j = nb[q];
            const uint4* p = (const uint4*)(x1 + j * 256 + cg * 16);
#pragma unroll
            for (int u = 0; u < 2; u++) {
                uint4 v = p[u];
                a[u*8+0] += bf2f((unsigned short)(v.x & 0xffff));
                a[u*8+1] += bf2f((unsigned short)(v.x >> 16));
                a[u*8+2] += bf2f((unsigned short)(v.y & 0xffff));
                a[u*8+3] += bf2f((unsigned short)(v.y >> 16));
                a[u*8+4] += bf2f((unsigned short)(v.z & 0xffff));
                a[u*8+5] += bf2f((unsigned short)(v.z >> 16));
                a[u*8+6] += bf2f((unsigned short)(v.w & 0xffff));
                a[u*8+7] += bf2f((unsigned short)(v.w >> 16));
            }
        }
        unsigned short* xp = (unsigned short*)&X2[row * 264 + cg * 16];
#pragma unroll
        for (int u = 0; u < 2; u++) {
            uint4 o;
            o.x = (unsigned)f2bf(a[u*8+0]*0.1f) | ((unsigned)f2bf(a[u*8+1]*0.1f) << 16);
            o.y = (unsigned)f2bf(a[u*8+2]*0.1f) | ((unsigned)f2bf(a[u*8+3]*0.1f) << 16);
            o.z = (unsigned)f2bf(a[u*8+4]*0.1f) | ((unsigned)f2bf(a[u*8+5]*0.1f) << 16);
            o.w = (unsigned)f2bf(a[u*8+6]*0.1f) | ((unsigned)f2bf(a[u*8+7]*0.1f) << 16);
            *(uint4*)(xp + u * 8) = o;
        }
    }

    f4v acc[4];
    for (int f = 0; f < 4; f++) acc[f] = (f4v){0.f, 0.f, 0.f, 0.f};

    int w = tid >> 6, lane = tid & 63;
    int quad = lane >> 4, l15 = lane & 15;

    for (int kc = 0; kc < 12; kc++) {
        int kb = kc * 64;
        int klocal = kb & 255;
        if (kc < 8 && tid < 128) {
            const unsigned short* asrc = (kb < 256) ? (const unsigned short*)hbf : x1;
            int row = tid >> 3, c8 = (tid & 7) * 8;
            uint4 v = *(const uint4*)(asrc + (m0 + row) * 256 + klocal + c8);
            *(uint4*)(&Al[row * 72 + c8]) = v;
        }
        {
            const unsigned short* bsrc = Wt + (kb >> 8) * 65536;
            int c8 = (tid & 7) * 8, rbase = tid >> 3;
            for (int r2 = 0; r2 < 8; r2++) {
                int n = r2 * 32 + rbase;
                uint4 v = *(const uint4*)(bsrc + n * 256 + klocal + c8);
                *(uint4*)(&Bl[n * 72 + c8]) = v;
            }
        }
        __syncthreads();
        for (int ks = 0; ks < 2; ks++) {
            s8v a;
            if (kc < 8)
                a = *(const s8v*)(&Al[l15 * 72 + ks * 32 + quad * 8]);
            else
                a = *(const s8v*)(&X2[l15 * 264 + klocal + ks * 32 + quad * 8]);
            for (int f = 0; f < 4; f++) {
                int n = w * 64 + f * 16 + l15;
                s8v b = *(const s8v*)(&Bl[n * 72 + ks * 32 + quad * 8]);
                acc[f] = __builtin_amdgcn_mfma_f32_16x16x32_bf16(a, b, acc[f], 0, 0, 0);
            }
        }
        __syncthreads();
    }

    float py[4][3] = {};
    for (int f = 0; f < 4; f++) {
        int col = w * 64 + f * 16 + l15;
        float cbv = cbl[col];
        float rw0 = rwl[col * 3], rw1 = rwl[col * 3 + 1], rw2 = rwl[col * 3 + 2];
        for (int r = 0; r < 4; r++) {
            int grow = m0 + quad * 4 + r;
            float cval = acc[f][r] + cbv;
            float hn = hdo[grow * 256 + col] + EPSC * tanhf(cval);
            hdo[grow * 256 + col] = hn;
            hbf[grow * 256 + col] = f2bf(hn);
            py[r][0] += hn * rw0; py[r][1] += hn * rw1; py[r][2] += hn * rw2;
        }
    }
    for (int off = 1; off < 16; off <<= 1)
        for (int r = 0; r < 4; r++)
            for (int j = 0; j < 3; j++)
                py[r][j] += __shfl_xor(py[r][j], off, 64);
    if (l15 == 0)
        for (int r = 0; r < 4; r++)
            for (int j = 0; j < 3; j++)
                yred[w][quad][r][j] = py[r][j];
    __syncthreads();
    if (w == 0 && l15 == 0) {
        for (int r = 0; r < 4; r++) {
            int grow = m0 + quad * 4 + r;
            for (int j = 0; j < 3; j++) {
                float yv = yred[0][quad][r][j] + yred[1][quad][r][j]
                         + yred[2][quad][r][j] + yred[3][quad][r][j] + rb[j];
                yout[grow * 3 + j] = yv;
                if (yfin) yfin[grow * 3 + j] = yv;
            }
        }
    }
}

extern "C" void kernel_launch(void* const* d_in, const int* in_sizes, int n_in,
                              void* d_out, int out_size, void* d_ws, size_t ws_size,
                              hipStream_t stream) {
    const float* lm = (const float*)d_in[0];
    const float* ew = (const float*)d_in[1];
    const float* eb = (const float*)d_in[2];
    const float* rw = (const float*)d_in[3];
    const float* rb = (const float*)d_in[4];
    const float* cw = (const float*)d_in[5];
    const float* cb = (const float*)d_in[6];

    float* out = (float*)d_out;
    float* y_out = out;
    float* h_out = out + 24576;
    float* x_out = out + 24576 + 2097152;
    float* lp_out = x_out + 24576;

    char* ws = (char*)d_ws;
    int* nbr = (int*)ws;                       ws += NN * KNN * sizeof(int);
    float4* pos4 = (float4*)ws;                ws += NN * sizeof(float4);
    char* uni = ws;
    unsigned short* hbf = (unsigned short*)uni;
    unsigned short* x1  = hbf + NN * DH;
    unsigned short* Wt  = x1 + NN * DH;

    prep_pos<<<NN / 256, 256, 0, stream>>>(lm, pos4);
    knn_wave<<<NN / 4, 512, 0, stream>>>(lm, pos4, nbr);
    prep_wt<<<768, 256, 0, stream>>>(cw, Wt);
    emb_kernel<<<NN, 256, 0, stream>>>(lm, ew, eb, rw, rb, h_out, hbf, x_out);
    for (int t = 0; t < TSTEPS; t++) {
        agg_kernel<<<NN / 4, 256, 0, stream>>>(hbf, x1, nbr);
        gemm_step<<<NN / 16, 256, 0, stream>>>(hbf, x1, nbr, Wt, cb, rw, rb, h_out,
                                               lp_out + t * 24576,
                                               (t == TSTEPS - 1) ? y_out : nullptr);
    }
}

// Round 4
// 502.579 us; speedup vs baseline: 1.0564x; 1.0564x over previous
//
#include <hip/hip_runtime.h>
#include <float.h>
#include <math.h>

#define NN 8192
#define DH 256
#define KNN 10
#define TSTEPS 10
#define EPSC 0.1f
#define CTILE 1024          // candidates staged in LDS per tile
#define QPB 16              // queries per block (16 waves of 64)

typedef short s8v __attribute__((ext_vector_type(8)));
typedef float f4v __attribute__((ext_vector_type(4)));

__device__ __forceinline__ float bf2f(unsigned short u) {
    union { unsigned u; float f; } c; c.u = ((unsigned)u) << 16; return c.f;
}
__device__ __forceinline__ unsigned short f2bf(float f) {
    union { float f; unsigned u; } c; c.f = f;
    unsigned r = c.u + 0x7FFF + ((c.u >> 16) & 1);
    return (unsigned short)(r >> 16);
}

// Wave-uniform top-10 kept as UNSIGNED DISTANCE BITS (IEEE order == uint order
// for non-negative floats). All values derive from readlane/ballot -> uniform
// -> compiler places the bubble network on the SCALAR pipe (s_min_u32 /
// s_max_u32 / s_cselect_b32), co-issuing with VALU. Strict '<' keeps earlier
// (lower-index) arrival on ties.
#define DECL_TOP10U \
    unsigned b0=0x7F7FFFFFu,b1=0x7F7FFFFFu,b2=0x7F7FFFFFu,b3=0x7F7FFFFFu, \
             b4=0x7F7FFFFFu,b5=0x7F7FFFFFu,b6=0x7F7FFFFFu,b7=0x7F7FFFFFu, \
             b8=0x7F7FFFFFu,b9=0x7F7FFFFFu; \
    int i0=-1,i1=-1,i2=-1,i3=-1,i4=-1,i5=-1,i6=-1,i7=-1,i8=-1,i9=-1;

#define BSTEPU(bk, ik) { \
    bool     _s  = _tu < bk; \
    unsigned _bn = _s ? _tu : bk; \
    _tu          = _s ? bk : _tu; \
    int      _in = _s ? _it : ik; \
    _it          = _s ? ik : _it; \
    bk = _bn; ik = _in; \
}

#define BUBBLE10U(dv, jv) do { \
    unsigned _tu = (dv); int _it = (jv); \
    BSTEPU(b0, i0) BSTEPU(b1, i1) BSTEPU(b2, i2) BSTEPU(b3, i3) BSTEPU(b4, i4) \
    BSTEPU(b5, i5) BSTEPU(b6, i6) BSTEPU(b7, i7) BSTEPU(b8, i8) BSTEPU(b9, i9) \
} while (0)

// ---------------- conv_ws [3][256][256] (k,n) -> bf16 Wt [3][n][k] ------------
__global__ void prep_wt(const float* __restrict__ W, unsigned short* __restrict__ Wt) {
    int e = blockIdx.x * 256 + threadIdx.x;
    int g = e >> 16; int rem = e & 65535;
    int n = rem >> 8; int k = rem & 255;
    Wt[e] = f2bf(W[g * 65536 + k * 256 + n]);
}

// ---------------- pos4[j] = {x, y, z, |p|^2} ----------------------------------
__global__ void prep_pos(const float* __restrict__ pos, float4* __restrict__ pos4) {
    int j = blockIdx.x * 256 + threadIdx.x;
    float x = pos[j * 3], y = pos[j * 3 + 1], z = pos[j * 3 + 2];
    float4 v; v.x = x; v.y = y; v.z = z; v.w = x * x + y * y + z * z;
    pos4[j] = v;
}

// ---------------- kNN: 1 wave/query, 16 queries/block, scalar-pipe inserts ----
// 512 blocks x 1024 threads: each block streams pos4 (512KB) through LDS ONCE
// for 16 queries (R2/R3 did it per 4 queries -> 1GB L2 traffic ~ 30us floor;
// now 256MB ~ 7us). Candidate filter: v_cmp vs SGPR threshold + ballot; pops
// are readlane-broadcast (no DS ops) into the SALU bubble network above.
__launch_bounds__(1024)
__global__ void knn_wave(const float* __restrict__ pos, const float4* __restrict__ pos4,
                         int* __restrict__ nbr) {
    __shared__ float4 cand[CTILE];
    int tid = threadIdx.x;
    int wv = tid >> 6, lane = tid & 63;
    int i = blockIdx.x * QPB + wv;               // query for this wave
    float xi = pos[i * 3], yi = pos[i * 3 + 1], zi = pos[i * 3 + 2];
    float sqi = xi * xi + yi * yi + zi * zi;
    int igrp = i & ~63;                          // the only 64-group containing i

    DECL_TOP10U;

    for (int tile = 0; tile < NN / CTILE; ++tile) {
        __syncthreads();
        cand[tid] = pos4[tile * CTILE + tid];    // 1024 threads, 1 float4 each
        __syncthreads();
#pragma unroll 4
        for (int u = 0; u < CTILE / 64; ++u) {
            int jgrp = tile * CTILE + u * 64;
            float4 c = cand[u * 64 + lane];
            int j = jgrp + lane;
            float m = c.x * xi + c.y * yi + c.z * zi;
            float d = (sqi + c.w) - 2.0f * m;
            d = fmaxf(d, 0.0f);                  // uint-order safety (rounding)
            if (jgrp == igrp) {                  // wave-uniform branch
                if (j == i) d = FLT_MAX;         // self-exclusion, one batch only
            }
            unsigned du = __float_as_uint(d);
            unsigned long long mask = __ballot(du < b9);
            while (mask) {
                int l = __ffsll(mask) - 1;
                mask &= mask - 1;
                unsigned dcu = (unsigned)__builtin_amdgcn_readlane((int)du, l);
                if (dcu < b9) {                  // recheck vs updated threshold
                    int jc = __builtin_amdgcn_readlane(j, l);
                    BUBBLE10U(dcu, jc);
                }
            }
        }
    }

    // rank 'lane' index via cndmask ladder (runs once)
    int jv = i0;
    jv = (lane >= 1) ? i1 : jv;
    jv = (lane >= 2) ? i2 : jv;
    jv = (lane >= 3) ? i3 : jv;
    jv = (lane >= 4) ? i4 : jv;
    jv = (lane >= 5) ? i5 : jv;
    jv = (lane >= 6) ? i6 : jv;
    jv = (lane >= 7) ? i7 : jv;
    jv = (lane >= 8) ? i8 : jv;
    jv = (lane >= 9) ? i9 : jv;
    if (lane < KNN) nbr[i * KNN + lane] = jv;
}

// ---------------- h = lm@emb_w + emb_b ; x = h@rw + rb ------------------------
__global__ void emb_kernel(const float* __restrict__ lm, const float* __restrict__ ew,
                           const float* __restrict__ eb, const float* __restrict__ rw,
                           const float* __restrict__ rb,
                           float* __restrict__ hdo, unsigned short* __restrict__ hbf,
                           float* __restrict__ xout) {
    __shared__ float s0[4], s1[4], s2[4];
    int i = blockIdx.x, d = threadIdx.x;
    float a0 = lm[i * 3], a1 = lm[i * 3 + 1], a2 = lm[i * 3 + 2];
    float h = eb[d] + a0 * ew[d] + a1 * ew[256 + d] + a2 * ew[512 + d];
    hdo[i * 256 + d] = h;
    hbf[i * 256 + d] = f2bf(h);
    float p0 = h * rw[d * 3], p1 = h * rw[d * 3 + 1], p2 = h * rw[d * 3 + 2];
    for (int off = 32; off; off >>= 1) {
        p0 += __shfl_down(p0, off, 64);
        p1 += __shfl_down(p1, off, 64);
        p2 += __shfl_down(p2, off, 64);
    }
    int lane = d & 63, wid = d >> 6;
    if (lane == 0) { s0[wid] = p0; s1[wid] = p1; s2[wid] = p2; }
    __syncthreads();
    if (d == 0) {
        xout[i * 3 + 0] = s0[0] + s0[1] + s0[2] + s0[3] + rb[0];
        xout[i * 3 + 1] = s1[0] + s1[1] + s1[2] + s1[3] + rb[1];
        xout[i * 3 + 2] = s2[0] + s2[1] + s2[2] + s2[3] + rb[2];
    }
}

// ---------------- hop-1: x1[i] = 0.1 * sum_{j in nbr(i)} hbf[j] ---------------
__global__ void agg_kernel(const unsigned short* __restrict__ src,
                           unsigned short* __restrict__ dst,
                           const int* __restrict__ nbr) {
    int tid = threadIdx.x;
    int wid = tid >> 6, lane = tid & 63;
    int node = blockIdx.x * 4 + wid;
    int d0 = lane * 4;
    float a0 = 0.f, a1 = 0.f, a2 = 0.f, a3 = 0.f;
    const int* nb = nbr + node * KNN;
    for (int q = 0; q < KNN; q++) {
        int j = nb[q];
        uint2 v = *(const uint2*)(src + j * 256 + d0);
        a0 += bf2f((unsigned short)(v.x & 0xffff));
        a1 += bf2f((unsigned short)(v.x >> 16));
        a2 += bf2f((unsigned short)(v.y & 0xffff));
        a3 += bf2f((unsigned short)(v.y >> 16));
    }
    uint2 o;
    o.x = (unsigned)f2bf(a0 * 0.1f) | ((unsigned)f2bf(a1 * 0.1f) << 16);
    o.y = (unsigned)f2bf(a2 * 0.1f) | ((unsigned)f2bf(a3 * 0.1f) << 16);
    *(uint2*)(dst + node * 256 + d0) = o;
}

// ------- fused: hop-2 gather + GEMM + Euler + readout. M-tile 16, grid 512 ----
__launch_bounds__(256)
__global__ void gemm_step(unsigned short* hbf,
                          const unsigned short* __restrict__ x1,
                          const int* __restrict__ nbr,
                          const unsigned short* __restrict__ Wt,
                          const float* __restrict__ cb,
                          const float* __restrict__ rw, const float* __restrict__ rb,
                          float* hdo, float* __restrict__ yout, float* yfin) {
    __shared__ __align__(16) short Al[16 * 72];
    __shared__ __align__(16) short Bl[256 * 72];
    __shared__ __align__(16) short X2[16 * 264];
    __shared__ float rwl[768];
    __shared__ float cbl[256];
    __shared__ float yred[4][4][4][3];     // [wave][quad][r][xyz]

    int tid = threadIdx.x;
    int m0 = blockIdx.x * 16;
    for (int idx = tid; idx < 768; idx += 256) rwl[idx] = rw[idx];
    cbl[tid] = cb[tid];

    // ---- fused hop-2 aggregation: X2[row][:] = bf16(0.1 * sum x1[nbr[row]]) ----
    {
        int row = tid >> 4, cg = tid & 15;          // 16 threads per row, 16 dims each
        const int* nb = nbr + (m0 + row) * KNN;
        float a[16];
#pragma unroll
        for (int e = 0; e < 16; e++) a[e] = 0.f;
        for (int q = 0; q < KNN; q++) {
            int j = nb[q];
            const uint4* p = (const uint4*)(x1 + j * 256 + cg * 16);
#pragma unroll
            for (int u = 0; u < 2; u++) {
                uint4 v = p[u];
                a[u*8+0] += bf2f((unsigned short)(v.x & 0xffff));
                a[u*8+1] += bf2f((unsigned short)(v.x >> 16));
                a[u*8+2] += bf2f((unsigned short)(v.y & 0xffff));
                a[u*8+3] += bf2f((unsigned short)(v.y >> 16));
                a[u*8+4] += bf2f((unsigned short)(v.z & 0xffff));
                a[u*8+5] += bf2f((unsigned short)(v.z >> 16));
                a[u*8+6] += bf2f((unsigned short)(v.w & 0xffff));
                a[u*8+7] += bf2f((unsigned short)(v.w >> 16));
            }
        }
        unsigned short* xp = (unsigned short*)&X2[row * 264 + cg * 16];
#pragma unroll
        for (int u = 0; u < 2; u++) {
            uint4 o;
            o.x = (unsigned)f2bf(a[u*8+0]*0.1f) | ((unsigned)f2bf(a[u*8+1]*0.1f) << 16);
            o.y = (unsigned)f2bf(a[u*8+2]*0.1f) | ((unsigned)f2bf(a[u*8+3]*0.1f) << 16);
            o.z = (unsigned)f2bf(a[u*8+4]*0.1f) | ((unsigned)f2bf(a[u*8+5]*0.1f) << 16);
            o.w = (unsigned)f2bf(a[u*8+6]*0.1f) | ((unsigned)f2bf(a[u*8+7]*0.1f) << 16);
            *(uint4*)(xp + u * 8) = o;
        }
    }

    f4v acc[4];
    for (int f = 0; f < 4; f++) acc[f] = (f4v){0.f, 0.f, 0.f, 0.f};

    int w = tid >> 6, lane = tid & 63;
    int quad = lane >> 4, l15 = lane & 15;

    for (int kc = 0; kc < 12; kc++) {
        int kb = kc * 64;
        int klocal = kb & 255;
        if (kc < 8 && tid < 128) {
            const unsigned short* asrc = (kb < 256) ? (const unsigned short*)hbf : x1;
            int row = tid >> 3, c8 = (tid & 7) * 8;
            uint4 v = *(const uint4*)(asrc + (m0 + row) * 256 + klocal + c8);
            *(uint4*)(&Al[row * 72 + c8]) = v;
        }
        {
            const unsigned short* bsrc = Wt + (kb >> 8) * 65536;
            int c8 = (tid & 7) * 8, rbase = tid >> 3;
            for (int r2 = 0; r2 < 8; r2++) {
                int n = r2 * 32 + rbase;
                uint4 v = *(const uint4*)(bsrc + n * 256 + klocal + c8);
                *(uint4*)(&Bl[n * 72 + c8]) = v;
            }
        }
        __syncthreads();
        for (int ks = 0; ks < 2; ks++) {
            s8v a;
            if (kc < 8)
                a = *(const s8v*)(&Al[l15 * 72 + ks * 32 + quad * 8]);
            else
                a = *(const s8v*)(&X2[l15 * 264 + klocal + ks * 32 + quad * 8]);
            for (int f = 0; f < 4; f++) {
                int n = w * 64 + f * 16 + l15;
                s8v b = *(const s8v*)(&Bl[n * 72 + ks * 32 + quad * 8]);
                acc[f] = __builtin_amdgcn_mfma_f32_16x16x32_bf16(a, b, acc[f], 0, 0, 0);
            }
        }
        __syncthreads();
    }

    float py[4][3] = {};
    for (int f = 0; f < 4; f++) {
        int col = w * 64 + f * 16 + l15;
        float cbv = cbl[col];
        float rw0 = rwl[col * 3], rw1 = rwl[col * 3 + 1], rw2 = rwl[col * 3 + 2];
        for (int r = 0; r < 4; r++) {
            int grow = m0 + quad * 4 + r;
            float cval = acc[f][r] + cbv;
            float hn = hdo[grow * 256 + col] + EPSC * tanhf(cval);
            hdo[grow * 256 + col] = hn;
            hbf[grow * 256 + col] = f2bf(hn);
            py[r][0] += hn * rw0; py[r][1] += hn * rw1; py[r][2] += hn * rw2;
        }
    }
    for (int off = 1; off < 16; off <<= 1)
        for (int r = 0; r < 4; r++)
            for (int j = 0; j < 3; j++)
                py[r][j] += __shfl_xor(py[r][j], off, 64);
    if (l15 == 0)
        for (int r = 0; r < 4; r++)
            for (int j = 0; j < 3; j++)
                yred[w][quad][r][j] = py[r][j];
    __syncthreads();
    if (w == 0 && l15 == 0) {
        for (int r = 0; r < 4; r++) {
            int grow = m0 + quad * 4 + r;
            for (int j = 0; j < 3; j++) {
                float yv = yred[0][quad][r][j] + yred[1][quad][r][j]
                         + yred[2][quad][r][j] + yred[3][quad][r][j] + rb[j];
                yout[grow * 3 + j] = yv;
                if (yfin) yfin[grow * 3 + j] = yv;
            }
        }
    }
}

extern "C" void kernel_launch(void* const* d_in, const int* in_sizes, int n_in,
                              void* d_out, int out_size, void* d_ws, size_t ws_size,
                              hipStream_t stream) {
    const float* lm = (const float*)d_in[0];
    const float* ew = (const float*)d_in[1];
    const float* eb = (const float*)d_in[2];
    const float* rw = (const float*)d_in[3];
    const float* rb = (const float*)d_in[4];
    const float* cw = (const float*)d_in[5];
    const float* cb = (const float*)d_in[6];

    float* out = (float*)d_out;
    float* y_out = out;
    float* h_out = out + 24576;
    float* x_out = out + 24576 + 2097152;
    float* lp_out = x_out + 24576;

    char* ws = (char*)d_ws;
    int* nbr = (int*)ws;                       ws += NN * KNN * sizeof(int);
    float4* pos4 = (float4*)ws;                ws += NN * sizeof(float4);
    char* uni = ws;
    unsigned short* hbf = (unsigned short*)uni;
    unsigned short* x1  = hbf + NN * DH;
    unsigned short* Wt  = x1 + NN * DH;

    prep_pos<<<NN / 256, 256, 0, stream>>>(lm, pos4);
    knn_wave<<<NN / QPB, 1024, 0, stream>>>(lm, pos4, nbr);
    prep_wt<<<768, 256, 0, stream>>>(cw, Wt);
    emb_kernel<<<NN, 256, 0, stream>>>(lm, ew, eb, rw, rb, h_out, hbf, x_out);
    for (int t = 0; t < TSTEPS; t++) {
        agg_kernel<<<NN / 4, 256, 0, stream>>>(hbf, x1, nbr);
        gemm_step<<<NN / 16, 256, 0, stream>>>(hbf, x1, nbr, Wt, cb, rw, rb, h_out,
                                               lp_out + t * 24576,
                                               (t == TSTEPS - 1) ? y_out : nullptr);
    }
}